// Round 1
// baseline (360.718 us; speedup 1.0000x reference)
//
#include <hip/hip_runtime.h>

#define D1 8
#define D2 16
#define HH 64
#define WW 64
#define SPATIAL (D1*D2*HH*WW)   // 524288
#define EPS 1e-5f
#define NEG 0.2f

typedef unsigned short u16;
typedef __attribute__((ext_vector_type(8))) short s16x8;
typedef __attribute__((ext_vector_type(8))) unsigned short u16x8;
typedef __attribute__((ext_vector_type(4))) unsigned short u16x4;
typedef __attribute__((ext_vector_type(4))) float f32x4;

__device__ __forceinline__ u16 f2bf(float f) {
    unsigned int u = __builtin_bit_cast(unsigned int, f);
    return (u16)((u + 0x7FFFu + ((u >> 16) & 1u)) >> 16);   // RNE
}
__device__ __forceinline__ float bf2f(u16 u) {
    unsigned int v = ((unsigned int)u) << 16;
    return __builtin_bit_cast(float, v);
}
__device__ __forceinline__ float leaky(float x) {
    return x >= 0.f ? x : NEG * x;
}

// XCD swizzle: b-PAIR per XCD (db-halo L2 reuse); h-tiles+a consecutive.
__device__ __forceinline__ void decode_block(int flat, int& a, int& b, int& h0) {
    int xcd  = flat & 7;
    int slot = flat >> 3;
    int ht   = slot & 7;
    int b0   = (slot >> 3) & 1;
    a        = (slot >> 4) & 7;
    b        = xcd * 2 + b0;
    h0       = ht * 8;
}

// ---------------------------------------------------------------------------
// prep: fused imgtrans (blocks 0..2047) + wtrans1 (2048..2263) +
//       wtrans2 (2264..2587) + stats-zero (2588).
// w1t: [p(9)][dh(3)][grp(2)][co(32)][k(32)]
// w2t: [p(9)][tap(9)][co(32)][ci(32)]
// imgT: [spatial][ci16] channel-last bf16
// ---------------------------------------------------------------------------
__global__ __launch_bounds__(256)
void prep(const float* __restrict__ img, const float* __restrict__ w1,
          const float* __restrict__ w2, u16* __restrict__ imgT,
          u16* __restrict__ w1t, u16* __restrict__ w2t, float* __restrict__ st)
{
    const int bid = blockIdx.x;
    const int tid = threadIdx.x;
    if (bid < 2048) {                          // image transpose
        int p = bid * 256 + tid;
        u16 r[16];
        #pragma unroll
        for (int c = 0; c < 16; ++c)
            r[c] = f2bf(img[(size_t)c * SPATIAL + p]);
        u16x8 lo, hi;
        #pragma unroll
        for (int j = 0; j < 8; ++j) { lo[j] = r[j]; hi[j] = r[8 + j]; }
        u16x8* dst = (u16x8*)(imgT + (size_t)p * 16);
        dst[0] = lo;
        dst[1] = hi;
    } else if (bid < 2264) {                   // w1 transform
        int i = (bid - 2048) * 256 + tid;
        if (i >= 55296) return;
        int k    = i & 31;
        int co   = (i >> 5) & 31;
        int grp  = (i >> 10) & 1;
        int rest = i >> 11;           // p*3+dh
        int dh   = rest % 3;
        int p    = rest / 3;
        int da = p / 3, db = p % 3;
        float v = 0.f;
        if (grp == 0) {
            int dw = k >> 4, ci = k & 15;
            v = w1[((((co * 16 + ci) * 3 + da) * 3 + db) * 3 + dh) * 3 + dw];
        } else if (k < 16) {
            v = w1[((((co * 16 + k) * 3 + da) * 3 + db) * 3 + dh) * 3 + 2];
        }
        w1t[i] = f2bf(v);
    } else if (bid < 2588) {                   // w2 transform
        int i = (bid - 2264) * 256 + tid;
        if (i >= 82944) return;
        int ci = i & 31;
        int co = (i >> 5) & 31;
        int t  = (i >> 10) % 9;
        int p  = (i >> 10) / 9;
        int da = p / 3, db = p % 3, dh = t / 3, dw = t % 3;
        w2t[i] = f2bf(w2[((((co * 32 + ci) * 3 + da) * 3 + db) * 3 + dh) * 3 + dw]);
    } else {                                   // stats zero
        if (tid < 128) st[tid] = 0.f;
    }
}

// ---------------------------------------------------------------------------
// Conv1: Cin=16, K = dw(2)x ci(16) packing + dw2 group. Row-shared A-frags.
// LDS pos stride 24 u16 (48B, 16B-aligned): 2-way banks -> free.
// B-frags software-pipelined ONE ROUND AHEAD (incl. across plane boundary):
// the round's MFMAs never wait on a just-issued global load.
// ---------------------------------------------------------------------------
__global__ __launch_bounds__(256, 3)
void conv1_mfma(const u16* __restrict__ xT, const u16* __restrict__ w1t,
                u16* __restrict__ y1, float* __restrict__ st1)
{
    __shared__ __align__(16) u16 lds[660 * 24];   // 31680 B
    __shared__ float sred[64];

    const int tid = threadIdx.x;
    int a, b, h0;
    decode_block(blockIdx.x, a, b, h0);
    const int lane = tid & 63;
    const int wv   = tid >> 6;
    const int kq   = lane >> 4;
    const int m    = lane & 15;
    const int wseg = wv << 4;

    unsigned pm = 0;
    #pragma unroll
    for (int p = 0; p < 9; ++p) {
        int ap = a + p / 3 - 1, bp = b + p % 3 - 1;
        if (ap >= 0 && ap < D1 && bp >= 0 && bp < D2) pm |= 1u << p;
    }

    // B-frag loader: w1t layout [p][dh][grp][co(32)][k(32)]
    auto ldbf = [&](s16x8 (&d)[3][2], const u16* wbase, int grp) {
        #pragma unroll
        for (int dh = 0; dh < 3; ++dh) {
            const u16* wb = wbase + (dh * 2 + grp) * 1024;
            d[dh][0] = *(const s16x8*)(wb + m * 32 + kq * 8);
            d[dh][1] = *(const s16x8*)(wb + (m + 16) * 32 + kq * 8);
        }
    };

    // plane-invariant staging offsets (6 granules/thread max, 16 B each)
    const int p0 = tid >> 1, g = tid & 1;
    unsigned vmask = 0;
    int goff[6];
    #pragma unroll
    for (int k = 0; k < 6; ++k) {
        int pos = p0 + 128 * k;
        int row = pos / 66, col = pos - row * 66;
        int h = h0 - 1 + row, w = col - 1;
        bool v = (pos < 660) && col >= 1 && col <= 64 && h >= 0 && h < HH;
        goff[k] = v ? (h * WW + w) * 16 + g * 8 : 0;
        vmask |= (unsigned)v << k;
    }
    const int lbase = p0 * 24 + g * 8;

    // zero pad/OOB cells once
    for (int e = tid; e < 660; e += 256) {
        int row = e / 66, col = e - row * 66;
        int h = h0 - 1 + row;
        if (col == 0 || col == 65 || h < 0 || h >= HH) {
            u16x8 z = (u16x8)0;
            *(u16x8*)&lds[e * 24]     = z;
            *(u16x8*)&lds[e * 24 + 8] = z;
        }
    }

    f32x4 acc[8][2];
    #pragma unroll
    for (int i = 0; i < 8; ++i)
        #pragma unroll
        for (int nt = 0; nt < 2; ++nt)
            acc[i][nt] = (f32x4)0.f;

    int p = 0;
    while (!((pm >> p) & 1)) ++p;

    // prologue: B-frags for (first plane, grp 0) in flight before staging
    s16x8 bf[3][2];
    ldbf(bf, w1t + p * 6144, 0);

    u16x8 pf[6];
    {
        int ap = a + p / 3 - 1, bp = b + p % 3 - 1;
        const u16* src = xT + (size_t)(ap * D2 + bp) * (HH * WW * 16);
        #pragma unroll
        for (int k = 0; k < 6; ++k)
            if ((vmask >> k) & 1) pf[k] = *(const u16x8*)(src + goff[k]);
    }

    while (p < 9) {
        int pn = p + 1;
        while (pn < 9 && !((pm >> pn) & 1)) ++pn;

        #pragma unroll
        for (int k = 0; k < 6; ++k)
            if ((vmask >> k) & 1) *(u16x8*)&lds[lbase + k * 3072] = pf[k];
        __syncthreads();

        const u16* srcn = nullptr;
        if (pn < 9)
            srcn = xT + (size_t)((a + pn / 3 - 1) * D2 + (b + pn % 3 - 1))
                      * (HH * WW * 16);

        const u16* wbase  = w1t + p * 6144;
        const u16* wbasen = (pn < 9) ? (w1t + pn * 6144) : nullptr;
        #pragma unroll
        for (int grp = 0; grp < 2; ++grp) {
            // prefetch NEXT round's B-frags (grp1 same plane, or grp0 next
            // plane — in-flight loads drain for free during the barrier)
            s16x8 bfn[3][2];
            const bool hn = (grp == 0) || (pn < 9);
            if (hn) ldbf(bfn, (grp == 0) ? wbase : wbasen, grp ^ 1);

            const int cshift = (grp == 0) ? (kq >> 1) : 2;
            const int ebase  = (kq & 1) * 8;
            #pragma unroll
            for (int x = 0; x < 10; ++x) {
                int pos = x * 66 + wseg + m + cshift;
                s16x8 af = *(const s16x8*)&lds[pos * 24 + ebase];
                #pragma unroll
                for (int dh = 0; dh < 3; ++dh) {
                    int i = x - dh;
                    if (i >= 0 && i < 8) {
                        acc[i][0] = __builtin_amdgcn_mfma_f32_16x16x32_bf16(af, bf[dh][0], acc[i][0], 0, 0, 0);
                        acc[i][1] = __builtin_amdgcn_mfma_f32_16x16x32_bf16(af, bf[dh][1], acc[i][1], 0, 0, 0);
                    }
                }
            }
            // progressive prefetch of next plane, under this grp's MFMAs
            if (pn < 9) {
                #pragma unroll
                for (int k = grp * 3; k < grp * 3 + 3; ++k)
                    if ((vmask >> k) & 1) pf[k] = *(const u16x8*)(srcn + goff[k]);
            }
            if (hn) {
                #pragma unroll
                for (int dh = 0; dh < 3; ++dh) {
                    bf[dh][0] = bfn[dh][0];
                    bf[dh][1] = bfn[dh][1];
                }
            }
        }
        __syncthreads();
        p = pn;
    }

    // epilogue: channel-last bf16 store + fused per-channel stats
    if (tid < 64) sred[tid] = 0.f;
    __syncthreads();

    float s[2] = {0.f, 0.f}, s2[2] = {0.f, 0.f};
    const size_t plane_out = (size_t)(a * D2 + b) * (HH * WW);
    #pragma unroll
    for (int i = 0; i < 8; ++i) {
        int h  = h0 + i;
        int w0 = wseg + kq * 4;
        #pragma unroll
        for (int nt = 0; nt < 2; ++nt) {
            int co = m + nt * 16;
            #pragma unroll
            for (int reg = 0; reg < 4; ++reg) {
                float v = acc[i][nt][reg];
                s[nt]  += v;
                s2[nt] += v * v;
                y1[(plane_out + h * WW + (w0 + reg)) * 32 + co] = f2bf(v);
            }
        }
    }
    #pragma unroll
    for (int nt = 0; nt < 2; ++nt) {
        s[nt]  += __shfl_xor(s[nt], 16);  s[nt]  += __shfl_xor(s[nt], 32);
        s2[nt] += __shfl_xor(s2[nt], 16); s2[nt] += __shfl_xor(s2[nt], 32);
    }
    if (kq == 0) {
        atomicAdd(&sred[m * 2],            s[0]);
        atomicAdd(&sred[m * 2 + 1],        s2[0]);
        atomicAdd(&sred[(m + 16) * 2],     s[1]);
        atomicAdd(&sred[(m + 16) * 2 + 1], s2[1]);
    }
    __syncthreads();
    if (tid < 64) atomicAdd(&st1[tid], sred[tid]);
}

// ---------------------------------------------------------------------------
// norm1: in-place instance-norm + leaky on y1 (channel-last bf16).
// ---------------------------------------------------------------------------
__global__ __launch_bounds__(256)
void norm1_kernel(u16* __restrict__ y1, const float* __restrict__ st1)
{
    const int tid = threadIdx.x;
    const int q   = tid & 3;
    const float invN = 1.f / (float)SPATIAL;
    float mean[8], scl[8];
    #pragma unroll
    for (int j = 0; j < 8; ++j) {
        int ci  = q * 8 + j;
        float mu = st1[ci * 2] * invN;
        float va = st1[ci * 2 + 1] * invN - mu * mu;
        mean[j] = mu;
        scl[j]  = rsqrtf(va + EPS);
    }
    #pragma unroll
    for (int j4 = 0; j4 < 4; ++j4) {
        size_t gidx = (size_t)blockIdx.x * 1024 + j4 * 256 + tid;
        u16x8* ptr = (u16x8*)(y1 + gidx * 8);
        u16x8 v = *ptr;
        u16x8 o;
        #pragma unroll
        for (int j = 0; j < 8; ++j)
            o[j] = f2bf(leaky((bf2f(v[j]) - mean[j]) * scl[j]));
        *ptr = o;
    }
}

// ---------------------------------------------------------------------------
// Conv2: Cin=32, row-shared A-frags; LDS pos stride 40 u16 (80B): 2-way free.
// B-frags software-pipelined ONE ROUND AHEAD (incl. across plane boundary).
// ---------------------------------------------------------------------------
__global__ __launch_bounds__(256, 3)
void conv2_mfma(const u16* __restrict__ y1, const u16* __restrict__ w2t,
                u16* __restrict__ y2, float* __restrict__ st2)
{
    __shared__ __align__(16) u16 lds[660 * 40];   // 52800 B
    __shared__ float sred[64];

    const int tid = threadIdx.x;
    int a, b, h0;
    decode_block(blockIdx.x, a, b, h0);
    const int lane = tid & 63;
    const int wv   = tid >> 6;
    const int kq   = lane >> 4;
    const int m    = lane & 15;
    const int wseg = wv << 4;

    unsigned pm = 0;
    #pragma unroll
    for (int p = 0; p < 9; ++p) {
        int ap = a + p / 3 - 1, bp = b + p % 3 - 1;
        if (ap >= 0 && ap < D1 && bp >= 0 && bp < D2) pm |= 1u << p;
    }

    // B-frag loader: w2t layout [p][tap(dh*3+dw)][co(32)][ci(32)]
    auto ldbf = [&](s16x8 (&d)[3][2], const u16* wbase, int dw) {
        #pragma unroll
        for (int dh = 0; dh < 3; ++dh) {
            const u16* wb = wbase + (dh * 3 + dw) * 1024;
            d[dh][0] = *(const s16x8*)(wb + m * 32 + kq * 8);
            d[dh][1] = *(const s16x8*)(wb + (m + 16) * 32 + kq * 8);
        }
    };

    // plane-invariant staging offsets (11 granules/thread max)
    const int p0 = tid >> 2, q = tid & 3;
    unsigned vmask = 0;
    int goff[11];
    #pragma unroll
    for (int k = 0; k < 11; ++k) {
        int pos = p0 + 64 * k;
        int row = pos / 66, col = pos - row * 66;
        int h = h0 - 1 + row, w = col - 1;
        bool v = (pos < 660) && col >= 1 && col <= 64 && h >= 0 && h < HH;
        goff[k] = v ? (h * WW + w) * 32 + q * 8 : 0;
        vmask |= (unsigned)v << k;
    }
    const int lbase = p0 * 40 + q * 8;

    for (int e = tid; e < 660; e += 256) {
        int row = e / 66, col = e - row * 66;
        int h = h0 - 1 + row;
        if (col == 0 || col == 65 || h < 0 || h >= HH) {
            u16x8 z = (u16x8)0;
            #pragma unroll
            for (int gg = 0; gg < 4; ++gg)
                *(u16x8*)&lds[e * 40 + gg * 8] = z;
        }
    }

    f32x4 acc[8][2];
    #pragma unroll
    for (int i = 0; i < 8; ++i)
        #pragma unroll
        for (int nt = 0; nt < 2; ++nt)
            acc[i][nt] = (f32x4)0.f;

    int p = 0;
    while (!((pm >> p) & 1)) ++p;

    // prologue: B-frags for (first plane, dw 0) in flight before staging
    s16x8 bf[3][2];
    ldbf(bf, w2t + p * 9216, 0);

    u16x8 pf[11];
    {
        int ap = a + p / 3 - 1, bp = b + p % 3 - 1;
        const u16* src = y1 + (size_t)(ap * D2 + bp) * (HH * WW * 32);
        #pragma unroll
        for (int k = 0; k < 11; ++k)
            if ((vmask >> k) & 1) pf[k] = *(const u16x8*)(src + goff[k]);
    }

    while (p < 9) {
        int pn = p + 1;
        while (pn < 9 && !((pm >> pn) & 1)) ++pn;

        #pragma unroll
        for (int k = 0; k < 11; ++k)
            if ((vmask >> k) & 1) *(u16x8*)&lds[lbase + k * 2560] = pf[k];
        __syncthreads();

        const u16* srcn = nullptr;
        if (pn < 9)
            srcn = y1 + (size_t)((a + pn / 3 - 1) * D2 + (b + pn % 3 - 1))
                      * (HH * WW * 32);

        const u16* wbase  = w2t + p * 9216;
        const u16* wbasen = (pn < 9) ? (w2t + pn * 9216) : nullptr;
        #pragma unroll
        for (int dw = 0; dw < 3; ++dw) {
            // prefetch NEXT round's B-frags (dw+1 same plane, or dw0 next
            // plane — in-flight loads drain for free during the barrier)
            s16x8 bfn[3][2];
            const bool hn = (dw < 2) || (pn < 9);
            if (hn) ldbf(bfn, (dw < 2) ? wbase : wbasen, (dw < 2) ? dw + 1 : 0);

            #pragma unroll
            for (int x = 0; x < 10; ++x) {
                int pos = x * 66 + wseg + dw + m;
                s16x8 af = *(const s16x8*)&lds[pos * 40 + kq * 8];
                #pragma unroll
                for (int dh = 0; dh < 3; ++dh) {
                    int i = x - dh;
                    if (i >= 0 && i < 8) {
                        acc[i][0] = __builtin_amdgcn_mfma_f32_16x16x32_bf16(af, bf[dh][0], acc[i][0], 0, 0, 0);
                        acc[i][1] = __builtin_amdgcn_mfma_f32_16x16x32_bf16(af, bf[dh][1], acc[i][1], 0, 0, 0);
                    }
                }
            }
            // progressive prefetch of next plane, under this dw's MFMAs
            if (pn < 9) {
                const int k0 = dw * 4;
                const int k1 = (dw == 2) ? 11 : (k0 + 4);
                #pragma unroll
                for (int k = k0; k < k1; ++k)
                    if ((vmask >> k) & 1) pf[k] = *(const u16x8*)(srcn + goff[k]);
            }
            if (hn) {
                #pragma unroll
                for (int dh = 0; dh < 3; ++dh) {
                    bf[dh][0] = bfn[dh][0];
                    bf[dh][1] = bfn[dh][1];
                }
            }
        }
        __syncthreads();
        p = pn;
    }

    // epilogue: channel-first bf16 + fused stats
    if (tid < 64) sred[tid] = 0.f;
    __syncthreads();

    float s[2] = {0.f, 0.f}, s2[2] = {0.f, 0.f};
    #pragma unroll
    for (int i = 0; i < 8; ++i) {
        int h  = h0 + i;
        int w0 = wseg + kq * 4;
        #pragma unroll
        for (int nt = 0; nt < 2; ++nt) {
            int co = m + nt * 16;
            u16x4 pk;
            #pragma unroll
            for (int reg = 0; reg < 4; ++reg) {
                float v = acc[i][nt][reg];
                s[nt]  += v;
                s2[nt] += v * v;
                pk[reg] = f2bf(v);
            }
            size_t off = ((size_t)(co * D1 + a) * D2 + b) * (HH * WW) + h * WW + w0;
            *(u16x4*)(y2 + off) = pk;
        }
    }
    #pragma unroll
    for (int nt = 0; nt < 2; ++nt) {
        s[nt]  += __shfl_xor(s[nt], 16);  s[nt]  += __shfl_xor(s[nt], 32);
        s2[nt] += __shfl_xor(s2[nt], 16); s2[nt] += __shfl_xor(s2[nt], 32);
    }
    if (kq == 0) {
        atomicAdd(&sred[m * 2],            s[0]);
        atomicAdd(&sred[m * 2 + 1],        s2[0]);
        atomicAdd(&sred[(m + 16) * 2],     s[1]);
        atomicAdd(&sred[(m + 16) * 2 + 1], s2[1]);
    }
    __syncthreads();
    if (tid < 64) atomicAdd(&st2[tid], sred[tid]);
}

// ---------------------------------------------------------------------------
// Final: norm + leaky, bf16 channel-first -> fp32 channel-first d_out
// ---------------------------------------------------------------------------
__global__ __launch_bounds__(256)
void norm2_kernel(const u16* __restrict__ y2, const float* __restrict__ st2,
                  float* __restrict__ out)
{
    size_t i4 = (size_t)blockIdx.x * 256 + threadIdx.x;
    int c = (int)(i4 >> 17);
    const float invN = 1.f / (float)SPATIAL;
    float mu = st2[c * 2] * invN;
    float va = st2[c * 2 + 1] * invN - mu * mu;
    float sc = rsqrtf(va + EPS);
    u16x4 v = *(const u16x4*)(y2 + i4 * 4);
    float4 o;
    o.x = leaky((bf2f(v[0]) - mu) * sc);
    o.y = leaky((bf2f(v[1]) - mu) * sc);
    o.z = leaky((bf2f(v[2]) - mu) * sc);
    o.w = leaky((bf2f(v[3]) - mu) * sc);
    *(float4*)(out + i4 * 4) = o;
}

// ---------------------------------------------------------------------------
extern "C" void kernel_launch(void* const* d_in, const int* in_sizes, int n_in,
                              void* d_out, int out_size, void* d_ws, size_t ws_size,
                              hipStream_t stream)
{
    const float* image = (const float*)d_in[0];
    const float* w1    = (const float*)d_in[1];
    const float* w2    = (const float*)d_in[2];
    float* out = (float*)d_out;

    // ws: [0,32MB) imgT (reused as y2) | [32MB,64MB) y1 | [64MB,+512B) stats
    u16*   imgT = (u16*)d_ws;
    u16*   y1   = (u16*)((char*)d_ws + 33554432);
    u16*   y2   = imgT;
    float* st   = (float*)((char*)d_ws + 67108864);
    float* st1  = st;
    float* st2  = st + 64;

    // weight tables live in d_out's tail; dead before norm2 overwrites d_out
    u16* w1t = (u16*)((char*)d_out + 66832384);   // 55296 bf16
    u16* w2t = (u16*)((char*)d_out + 66942976);   // 82944 bf16

    prep<<<2589, 256, 0, stream>>>(image, w1, w2, imgT, w1t, w2t, st);

    conv1_mfma<<<1024, 256, 0, stream>>>(imgT, w1t, y1, st1);
    norm1_kernel<<<2048, 256, 0, stream>>>(y1, st1);
    conv2_mfma<<<1024, 256, 0, stream>>>(y1, w2t, y2, st2);
    norm2_kernel<<<16384, 256, 0, stream>>>(y2, st2, out);
}

// Round 2
// 341.037 us; speedup vs baseline: 1.0577x; 1.0577x over previous
//
#include <hip/hip_runtime.h>

#define D1 8
#define D2 16
#define HH 64
#define WW 64
#define SPATIAL (D1*D2*HH*WW)   // 524288
#define EPS 1e-5f
#define NEG 0.2f

typedef unsigned short u16;
typedef __attribute__((ext_vector_type(8))) short s16x8;
typedef __attribute__((ext_vector_type(8))) unsigned short u16x8;
typedef __attribute__((ext_vector_type(4))) unsigned short u16x4;
typedef __attribute__((ext_vector_type(4))) float f32x4;

__device__ __forceinline__ u16 f2bf(float f) {
    unsigned int u = __builtin_bit_cast(unsigned int, f);
    return (u16)((u + 0x7FFFu + ((u >> 16) & 1u)) >> 16);   // RNE
}
__device__ __forceinline__ float bf2f(u16 u) {
    unsigned int v = ((unsigned int)u) << 16;
    return __builtin_bit_cast(float, v);
}
__device__ __forceinline__ float leaky(float x) {
    return x >= 0.f ? x : NEG * x;
}

// XCD swizzle: b-PAIR per XCD (db-halo L2 reuse); h-tiles+a consecutive.
__device__ __forceinline__ void decode_block(int flat, int& a, int& b, int& h0) {
    int xcd  = flat & 7;
    int slot = flat >> 3;
    int ht   = slot & 7;
    int b0   = (slot >> 3) & 1;
    a        = (slot >> 4) & 7;
    b        = xcd * 2 + b0;
    h0       = ht * 8;
}

// ---------------------------------------------------------------------------
// prep: fused imgtrans (blocks 0..2047) + wtrans1 (2048..2263) +
//       wtrans2 (2264..2587) + stats-zero (2588).
// w1t: [p(9)][dh(3)][grp(2)][co(32)][k(32)]
// w2t: [p(9)][tap(9)][co(32)][ci(32)]
// imgT: [spatial][ci16] channel-last bf16
// ---------------------------------------------------------------------------
__global__ __launch_bounds__(256)
void prep(const float* __restrict__ img, const float* __restrict__ w1,
          const float* __restrict__ w2, u16* __restrict__ imgT,
          u16* __restrict__ w1t, u16* __restrict__ w2t, float* __restrict__ st)
{
    const int bid = blockIdx.x;
    const int tid = threadIdx.x;
    if (bid < 2048) {                          // image transpose
        int p = bid * 256 + tid;
        u16 r[16];
        #pragma unroll
        for (int c = 0; c < 16; ++c)
            r[c] = f2bf(img[(size_t)c * SPATIAL + p]);
        u16x8 lo, hi;
        #pragma unroll
        for (int j = 0; j < 8; ++j) { lo[j] = r[j]; hi[j] = r[8 + j]; }
        u16x8* dst = (u16x8*)(imgT + (size_t)p * 16);
        dst[0] = lo;
        dst[1] = hi;
    } else if (bid < 2264) {                   // w1 transform
        int i = (bid - 2048) * 256 + tid;
        if (i >= 55296) return;
        int k    = i & 31;
        int co   = (i >> 5) & 31;
        int grp  = (i >> 10) & 1;
        int rest = i >> 11;           // p*3+dh
        int dh   = rest % 3;
        int p    = rest / 3;
        int da = p / 3, db = p % 3;
        float v = 0.f;
        if (grp == 0) {
            int dw = k >> 4, ci = k & 15;
            v = w1[((((co * 16 + ci) * 3 + da) * 3 + db) * 3 + dh) * 3 + dw];
        } else if (k < 16) {
            v = w1[((((co * 16 + k) * 3 + da) * 3 + db) * 3 + dh) * 3 + 2];
        }
        w1t[i] = f2bf(v);
    } else if (bid < 2588) {                   // w2 transform
        int i = (bid - 2264) * 256 + tid;
        if (i >= 82944) return;
        int ci = i & 31;
        int co = (i >> 5) & 31;
        int t  = (i >> 10) % 9;
        int p  = (i >> 10) / 9;
        int da = p / 3, db = p % 3, dh = t / 3, dw = t % 3;
        w2t[i] = f2bf(w2[((((co * 32 + ci) * 3 + da) * 3 + db) * 3 + dh) * 3 + dw]);
    } else {                                   // stats zero
        if (tid < 128) st[tid] = 0.f;
    }
}

// ---- spill-proof inline B-frag load / MFMA round macros (NO lambdas: an
// array-by-reference lambda param defeats SROA -> scratch; round-1 lesson) ----
#define C1_LDBF(DST, BASE, GRP) { \
    _Pragma("unroll") \
    for (int dh_ = 0; dh_ < 3; ++dh_) { \
        const u16* wb_ = (BASE) + (dh_ * 2 + (GRP)) * 1024; \
        DST[dh_][0] = *(const s16x8*)(wb_ + m * 32 + kq * 8); \
        DST[dh_][1] = *(const s16x8*)(wb_ + (m + 16) * 32 + kq * 8); \
    } }

#define C1_MFMA(BF, CSHIFT) { \
    const int eb_ = (kq & 1) * 8; \
    _Pragma("unroll") \
    for (int x_ = 0; x_ < 10; ++x_) { \
        int pos_ = x_ * 66 + wseg + m + (CSHIFT); \
        s16x8 af_ = *(const s16x8*)&lds[pos_ * 24 + eb_]; \
        _Pragma("unroll") \
        for (int dh_ = 0; dh_ < 3; ++dh_) { \
            int i_ = x_ - dh_; \
            if (i_ >= 0 && i_ < 8) { \
                acc[i_][0] = __builtin_amdgcn_mfma_f32_16x16x32_bf16(af_, BF[dh_][0], acc[i_][0], 0, 0, 0); \
                acc[i_][1] = __builtin_amdgcn_mfma_f32_16x16x32_bf16(af_, BF[dh_][1], acc[i_][1], 0, 0, 0); \
            } \
        } \
    } }

// ---------------------------------------------------------------------------
// Conv1: Cin=16, K = dw(2)x ci(16) packing + dw2 group. Row-shared A-frags.
// LDS pos stride 24 u16 (48B, 16B-aligned): 2-way banks -> free.
// B-frags ping-pong pipelined one round ahead (bf0/bf1, 2 rounds/plane):
// a round's MFMAs never wait on a just-issued global load.
// ---------------------------------------------------------------------------
__global__ __launch_bounds__(256, 3)
void conv1_mfma(const u16* __restrict__ xT, const u16* __restrict__ w1t,
                u16* __restrict__ y1, float* __restrict__ st1)
{
    __shared__ __align__(16) u16 lds[660 * 24];   // 31680 B
    __shared__ float sred[64];

    const int tid = threadIdx.x;
    int a, b, h0;
    decode_block(blockIdx.x, a, b, h0);
    const int lane = tid & 63;
    const int wv   = tid >> 6;
    const int kq   = lane >> 4;
    const int m    = lane & 15;
    const int wseg = wv << 4;

    unsigned pm = 0;
    #pragma unroll
    for (int p = 0; p < 9; ++p) {
        int ap = a + p / 3 - 1, bp = b + p % 3 - 1;
        if (ap >= 0 && ap < D1 && bp >= 0 && bp < D2) pm |= 1u << p;
    }

    // plane-invariant staging offsets (6 granules/thread max, 16 B each)
    const int p0 = tid >> 1, g = tid & 1;
    unsigned vmask = 0;
    int goff[6];
    #pragma unroll
    for (int k = 0; k < 6; ++k) {
        int pos = p0 + 128 * k;
        int row = pos / 66, col = pos - row * 66;
        int h = h0 - 1 + row, w = col - 1;
        bool v = (pos < 660) && col >= 1 && col <= 64 && h >= 0 && h < HH;
        goff[k] = v ? (h * WW + w) * 16 + g * 8 : 0;
        vmask |= (unsigned)v << k;
    }
    const int lbase = p0 * 24 + g * 8;

    // zero pad/OOB cells once
    for (int e = tid; e < 660; e += 256) {
        int row = e / 66, col = e - row * 66;
        int h = h0 - 1 + row;
        if (col == 0 || col == 65 || h < 0 || h >= HH) {
            u16x8 z = (u16x8)0;
            *(u16x8*)&lds[e * 24]     = z;
            *(u16x8*)&lds[e * 24 + 8] = z;
        }
    }

    f32x4 acc[8][2];
    #pragma unroll
    for (int i = 0; i < 8; ++i)
        #pragma unroll
        for (int nt = 0; nt < 2; ++nt)
            acc[i][nt] = (f32x4)0.f;

    int p = 0;
    while (!((pm >> p) & 1)) ++p;

    // prologue: B-frags for (first plane, grp0) in flight before staging
    s16x8 bf0[3][2], bf1[3][2];
    C1_LDBF(bf0, w1t + p * 6144, 0);

    u16x8 pf[6];
    {
        int ap = a + p / 3 - 1, bp = b + p % 3 - 1;
        const u16* src = xT + (size_t)(ap * D2 + bp) * (HH * WW * 16);
        #pragma unroll
        for (int k = 0; k < 6; ++k)
            if ((vmask >> k) & 1) pf[k] = *(const u16x8*)(src + goff[k]);
    }

    while (p < 9) {
        int pn = p + 1;
        while (pn < 9 && !((pm >> pn) & 1)) ++pn;

        #pragma unroll
        for (int k = 0; k < 6; ++k)
            if ((vmask >> k) & 1) *(u16x8*)&lds[lbase + k * 3072] = pf[k];
        __syncthreads();

        const u16* srcn = nullptr;
        if (pn < 9)
            srcn = xT + (size_t)((a + pn / 3 - 1) * D2 + (b + pn % 3 - 1))
                      * (HH * WW * 16);

        const u16* wbase  = w1t + p * 6144;
        const u16* wbasen = w1t + (pn < 9 ? pn : p) * 6144;

        // ---- round grp0: compute bf0; prefetch (p, grp1) -> bf1
        C1_LDBF(bf1, wbase, 1);
        C1_MFMA(bf0, (kq >> 1));
        if (pn < 9) {
            #pragma unroll
            for (int k = 0; k < 3; ++k)
                if ((vmask >> k) & 1) pf[k] = *(const u16x8*)(srcn + goff[k]);
        }

        // ---- round grp1: compute bf1; prefetch (pn, grp0) -> bf0
        if (pn < 9) C1_LDBF(bf0, wbasen, 0);
        C1_MFMA(bf1, 2);
        if (pn < 9) {
            #pragma unroll
            for (int k = 3; k < 6; ++k)
                if ((vmask >> k) & 1) pf[k] = *(const u16x8*)(srcn + goff[k]);
        }

        __syncthreads();
        p = pn;
    }

    // epilogue: channel-last bf16 store + fused per-channel stats
    if (tid < 64) sred[tid] = 0.f;
    __syncthreads();

    float s[2] = {0.f, 0.f}, s2[2] = {0.f, 0.f};
    const size_t plane_out = (size_t)(a * D2 + b) * (HH * WW);
    #pragma unroll
    for (int i = 0; i < 8; ++i) {
        int h  = h0 + i;
        int w0 = wseg + kq * 4;
        #pragma unroll
        for (int nt = 0; nt < 2; ++nt) {
            int co = m + nt * 16;
            #pragma unroll
            for (int reg = 0; reg < 4; ++reg) {
                float v = acc[i][nt][reg];
                s[nt]  += v;
                s2[nt] += v * v;
                y1[(plane_out + h * WW + (w0 + reg)) * 32 + co] = f2bf(v);
            }
        }
    }
    #pragma unroll
    for (int nt = 0; nt < 2; ++nt) {
        s[nt]  += __shfl_xor(s[nt], 16);  s[nt]  += __shfl_xor(s[nt], 32);
        s2[nt] += __shfl_xor(s2[nt], 16); s2[nt] += __shfl_xor(s2[nt], 32);
    }
    if (kq == 0) {
        atomicAdd(&sred[m * 2],            s[0]);
        atomicAdd(&sred[m * 2 + 1],        s2[0]);
        atomicAdd(&sred[(m + 16) * 2],     s[1]);
        atomicAdd(&sred[(m + 16) * 2 + 1], s2[1]);
    }
    __syncthreads();
    if (tid < 64) atomicAdd(&st1[tid], sred[tid]);
}

// ---------------------------------------------------------------------------
// norm1: in-place instance-norm + leaky on y1 (channel-last bf16).
// ---------------------------------------------------------------------------
__global__ __launch_bounds__(256)
void norm1_kernel(u16* __restrict__ y1, const float* __restrict__ st1)
{
    const int tid = threadIdx.x;
    const int q   = tid & 3;
    const float invN = 1.f / (float)SPATIAL;
    float mean[8], scl[8];
    #pragma unroll
    for (int j = 0; j < 8; ++j) {
        int ci  = q * 8 + j;
        float mu = st1[ci * 2] * invN;
        float va = st1[ci * 2 + 1] * invN - mu * mu;
        mean[j] = mu;
        scl[j]  = rsqrtf(va + EPS);
    }
    #pragma unroll
    for (int j4 = 0; j4 < 4; ++j4) {
        size_t gidx = (size_t)blockIdx.x * 1024 + j4 * 256 + tid;
        u16x8* ptr = (u16x8*)(y1 + gidx * 8);
        u16x8 v = *ptr;
        u16x8 o;
        #pragma unroll
        for (int j = 0; j < 8; ++j)
            o[j] = f2bf(leaky((bf2f(v[j]) - mean[j]) * scl[j]));
        *ptr = o;
    }
}

#define C2_LDBF(DST, BASE, DW) { \
    _Pragma("unroll") \
    for (int dh_ = 0; dh_ < 3; ++dh_) { \
        const u16* wb_ = (BASE) + (dh_ * 3 + (DW)) * 1024; \
        DST[dh_][0] = *(const s16x8*)(wb_ + m * 32 + kq * 8); \
        DST[dh_][1] = *(const s16x8*)(wb_ + (m + 16) * 32 + kq * 8); \
    } }

#define C2_MFMA(BF, DW) { \
    _Pragma("unroll") \
    for (int x_ = 0; x_ < 10; ++x_) { \
        int pos_ = x_ * 66 + wseg + (DW) + m; \
        s16x8 af_ = *(const s16x8*)&lds[pos_ * 40 + kq * 8]; \
        _Pragma("unroll") \
        for (int dh_ = 0; dh_ < 3; ++dh_) { \
            int i_ = x_ - dh_; \
            if (i_ >= 0 && i_ < 8) { \
                acc[i_][0] = __builtin_amdgcn_mfma_f32_16x16x32_bf16(af_, BF[dh_][0], acc[i_][0], 0, 0, 0); \
                acc[i_][1] = __builtin_amdgcn_mfma_f32_16x16x32_bf16(af_, BF[dh_][1], acc[i_][1], 0, 0, 0); \
            } \
        } \
    } }

#define C2_PF(K0, K1) { \
    _Pragma("unroll") \
    for (int k_ = (K0); k_ < (K1); ++k_) \
        if ((vmask >> k_) & 1) pf[k_] = *(const u16x8*)(srcn + goff[k_]); }

// ---------------------------------------------------------------------------
// Conv2: Cin=32, row-shared A-frags; LDS pos stride 40 u16 (80B): 2-way free.
// B-frags ping-pong pipelined one round ahead (bfA/bfB, 3 rounds/plane,
// one 6-frag register copy per plane restores the entry invariant).
// ---------------------------------------------------------------------------
__global__ __launch_bounds__(256, 3)
void conv2_mfma(const u16* __restrict__ y1, const u16* __restrict__ w2t,
                u16* __restrict__ y2, float* __restrict__ st2)
{
    __shared__ __align__(16) u16 lds[660 * 40];   // 52800 B
    __shared__ float sred[64];

    const int tid = threadIdx.x;
    int a, b, h0;
    decode_block(blockIdx.x, a, b, h0);
    const int lane = tid & 63;
    const int wv   = tid >> 6;
    const int kq   = lane >> 4;
    const int m    = lane & 15;
    const int wseg = wv << 4;

    unsigned pm = 0;
    #pragma unroll
    for (int p = 0; p < 9; ++p) {
        int ap = a + p / 3 - 1, bp = b + p % 3 - 1;
        if (ap >= 0 && ap < D1 && bp >= 0 && bp < D2) pm |= 1u << p;
    }

    // plane-invariant staging offsets (11 granules/thread max)
    const int p0 = tid >> 2, q = tid & 3;
    unsigned vmask = 0;
    int goff[11];
    #pragma unroll
    for (int k = 0; k < 11; ++k) {
        int pos = p0 + 64 * k;
        int row = pos / 66, col = pos - row * 66;
        int h = h0 - 1 + row, w = col - 1;
        bool v = (pos < 660) && col >= 1 && col <= 64 && h >= 0 && h < HH;
        goff[k] = v ? (h * WW + w) * 32 + q * 8 : 0;
        vmask |= (unsigned)v << k;
    }
    const int lbase = p0 * 40 + q * 8;

    for (int e = tid; e < 660; e += 256) {
        int row = e / 66, col = e - row * 66;
        int h = h0 - 1 + row;
        if (col == 0 || col == 65 || h < 0 || h >= HH) {
            u16x8 z = (u16x8)0;
            #pragma unroll
            for (int gg = 0; gg < 4; ++gg)
                *(u16x8*)&lds[e * 40 + gg * 8] = z;
        }
    }

    f32x4 acc[8][2];
    #pragma unroll
    for (int i = 0; i < 8; ++i)
        #pragma unroll
        for (int nt = 0; nt < 2; ++nt)
            acc[i][nt] = (f32x4)0.f;

    int p = 0;
    while (!((pm >> p) & 1)) ++p;

    // prologue: B-frags for (first plane, dw0) in flight before staging
    s16x8 bfA[3][2], bfB[3][2];
    C2_LDBF(bfA, w2t + p * 9216, 0);

    u16x8 pf[11];
    {
        int ap = a + p / 3 - 1, bp = b + p % 3 - 1;
        const u16* src = y1 + (size_t)(ap * D2 + bp) * (HH * WW * 32);
        #pragma unroll
        for (int k = 0; k < 11; ++k)
            if ((vmask >> k) & 1) pf[k] = *(const u16x8*)(src + goff[k]);
    }

    while (p < 9) {
        int pn = p + 1;
        while (pn < 9 && !((pm >> pn) & 1)) ++pn;

        #pragma unroll
        for (int k = 0; k < 11; ++k)
            if ((vmask >> k) & 1) *(u16x8*)&lds[lbase + k * 2560] = pf[k];
        __syncthreads();

        const u16* srcn = nullptr;
        if (pn < 9)
            srcn = y1 + (size_t)((a + pn / 3 - 1) * D2 + (b + pn % 3 - 1))
                      * (HH * WW * 32);

        const u16* wbase  = w2t + p * 9216;
        const u16* wbasen = w2t + (pn < 9 ? pn : p) * 9216;

        // r0 (dw0): compute bfA; prefetch (p, dw1) -> bfB
        C2_LDBF(bfB, wbase, 1);
        C2_MFMA(bfA, 0);
        if (pn < 9) C2_PF(0, 4);

        // r1 (dw1): compute bfB; prefetch (p, dw2) -> bfA (dw0 data dead)
        C2_LDBF(bfA, wbase, 2);
        C2_MFMA(bfB, 1);
        if (pn < 9) C2_PF(4, 8);

        // r2 (dw2): compute bfA; prefetch (pn, dw0) -> bfB
        if (pn < 9) C2_LDBF(bfB, wbasen, 0);
        C2_MFMA(bfA, 2);
        if (pn < 9) C2_PF(8, 11);

        // restore entry invariant: bfA holds next plane's dw0 (6 v_mov_b32x4)
        if (pn < 9) {
            #pragma unroll
            for (int dh = 0; dh < 3; ++dh) {
                bfA[dh][0] = bfB[dh][0];
                bfA[dh][1] = bfB[dh][1];
            }
        }

        __syncthreads();
        p = pn;
    }

    // epilogue: channel-first bf16 + fused stats
    if (tid < 64) sred[tid] = 0.f;
    __syncthreads();

    float s[2] = {0.f, 0.f}, s2[2] = {0.f, 0.f};
    #pragma unroll
    for (int i = 0; i < 8; ++i) {
        int h  = h0 + i;
        int w0 = wseg + kq * 4;
        #pragma unroll
        for (int nt = 0; nt < 2; ++nt) {
            int co = m + nt * 16;
            u16x4 pk;
            #pragma unroll
            for (int reg = 0; reg < 4; ++reg) {
                float v = acc[i][nt][reg];
                s[nt]  += v;
                s2[nt] += v * v;
                pk[reg] = f2bf(v);
            }
            size_t off = ((size_t)(co * D1 + a) * D2 + b) * (HH * WW) + h * WW + w0;
            *(u16x4*)(y2 + off) = pk;
        }
    }
    #pragma unroll
    for (int nt = 0; nt < 2; ++nt) {
        s[nt]  += __shfl_xor(s[nt], 16);  s[nt]  += __shfl_xor(s[nt], 32);
        s2[nt] += __shfl_xor(s2[nt], 16); s2[nt] += __shfl_xor(s2[nt], 32);
    }
    if (kq == 0) {
        atomicAdd(&sred[m * 2],            s[0]);
        atomicAdd(&sred[m * 2 + 1],        s2[0]);
        atomicAdd(&sred[(m + 16) * 2],     s[1]);
        atomicAdd(&sred[(m + 16) * 2 + 1], s2[1]);
    }
    __syncthreads();
    if (tid < 64) atomicAdd(&st2[tid], sred[tid]);
}

// ---------------------------------------------------------------------------
// Final: norm + leaky, bf16 channel-first -> fp32 channel-first d_out
// ---------------------------------------------------------------------------
__global__ __launch_bounds__(256)
void norm2_kernel(const u16* __restrict__ y2, const float* __restrict__ st2,
                  float* __restrict__ out)
{
    size_t i4 = (size_t)blockIdx.x * 256 + threadIdx.x;
    int c = (int)(i4 >> 17);
    const float invN = 1.f / (float)SPATIAL;
    float mu = st2[c * 2] * invN;
    float va = st2[c * 2 + 1] * invN - mu * mu;
    float sc = rsqrtf(va + EPS);
    u16x4 v = *(const u16x4*)(y2 + i4 * 4);
    float4 o;
    o.x = leaky((bf2f(v[0]) - mu) * sc);
    o.y = leaky((bf2f(v[1]) - mu) * sc);
    o.z = leaky((bf2f(v[2]) - mu) * sc);
    o.w = leaky((bf2f(v[3]) - mu) * sc);
    *(float4*)(out + i4 * 4) = o;
}

// ---------------------------------------------------------------------------
extern "C" void kernel_launch(void* const* d_in, const int* in_sizes, int n_in,
                              void* d_out, int out_size, void* d_ws, size_t ws_size,
                              hipStream_t stream)
{
    const float* image = (const float*)d_in[0];
    const float* w1    = (const float*)d_in[1];
    const float* w2    = (const float*)d_in[2];
    float* out = (float*)d_out;

    // ws: [0,32MB) imgT (reused as y2) | [32MB,64MB) y1 | [64MB,+512B) stats
    u16*   imgT = (u16*)d_ws;
    u16*   y1   = (u16*)((char*)d_ws + 33554432);
    u16*   y2   = imgT;
    float* st   = (float*)((char*)d_ws + 67108864);
    float* st1  = st;
    float* st2  = st + 64;

    // weight tables live in d_out's tail; dead before norm2 overwrites d_out
    u16* w1t = (u16*)((char*)d_out + 66832384);   // 55296 bf16
    u16* w2t = (u16*)((char*)d_out + 66942976);   // 82944 bf16

    prep<<<2589, 256, 0, stream>>>(image, w1, w2, imgT, w1t, w2t, st);

    conv1_mfma<<<1024, 256, 0, stream>>>(imgT, w1t, y1, st1);
    norm1_kernel<<<2048, 256, 0, stream>>>(y1, st1);
    conv2_mfma<<<1024, 256, 0, stream>>>(y1, w2t, y2, st2);
    norm2_kernel<<<16384, 256, 0, stream>>>(y2, st2, out);
}

// Round 3
// 257.277 us; speedup vs baseline: 1.4021x; 1.3256x over previous
//
#include <hip/hip_runtime.h>

#define D1 8
#define D2 16
#define HH 64
#define WW 64
#define SPATIAL (D1*D2*HH*WW)   // 524288
#define EPS 1e-5f
#define NEG 0.2f

typedef unsigned short u16;
typedef __attribute__((ext_vector_type(8))) short s16x8;
typedef __attribute__((ext_vector_type(8))) unsigned short u16x8;
typedef __attribute__((ext_vector_type(4))) unsigned short u16x4;
typedef __attribute__((ext_vector_type(4))) float f32x4;

__device__ __forceinline__ u16 f2bf(float f) {
    unsigned int u = __builtin_bit_cast(unsigned int, f);
    return (u16)((u + 0x7FFFu + ((u >> 16) & 1u)) >> 16);   // RNE
}
__device__ __forceinline__ float bf2f(u16 u) {
    unsigned int v = ((unsigned int)u) << 16;
    return __builtin_bit_cast(float, v);
}
__device__ __forceinline__ float leaky(float x) {
    return x >= 0.f ? x : NEG * x;
}

// XCD swizzle: b-PAIR per XCD (db-halo L2 reuse); h-tiles+a consecutive.
__device__ __forceinline__ void decode_block(int flat, int& a, int& b, int& h0) {
    int xcd  = flat & 7;
    int slot = flat >> 3;
    int ht   = slot & 7;
    int b0   = (slot >> 3) & 1;
    a        = (slot >> 4) & 7;
    b        = xcd * 2 + b0;
    h0       = ht * 8;
}

// ---------------------------------------------------------------------------
// prep: fused imgtrans (blocks 0..2047) + wtrans1 (2048..2263) +
//       wtrans2 (2264..2587) + stats-zero (2588).
// w1t: [p(9)][dh(3)][grp(2)][co(32)][k(32)]
// w2t: [p(9)][tap(9)][co(32)][ci(32)]
// imgT: [spatial][ci16] channel-last bf16
// ---------------------------------------------------------------------------
__global__ __launch_bounds__(256)
void prep(const float* __restrict__ img, const float* __restrict__ w1,
          const float* __restrict__ w2, u16* __restrict__ imgT,
          u16* __restrict__ w1t, u16* __restrict__ w2t, float* __restrict__ st)
{
    const int bid = blockIdx.x;
    const int tid = threadIdx.x;
    if (bid < 2048) {                          // image transpose
        int p = bid * 256 + tid;
        u16 r[16];
        #pragma unroll
        for (int c = 0; c < 16; ++c)
            r[c] = f2bf(img[(size_t)c * SPATIAL + p]);
        u16x8 lo, hi;
        #pragma unroll
        for (int j = 0; j < 8; ++j) { lo[j] = r[j]; hi[j] = r[8 + j]; }
        u16x8* dst = (u16x8*)(imgT + (size_t)p * 16);
        dst[0] = lo;
        dst[1] = hi;
    } else if (bid < 2264) {                   // w1 transform
        int i = (bid - 2048) * 256 + tid;
        if (i >= 55296) return;
        int k    = i & 31;
        int co   = (i >> 5) & 31;
        int grp  = (i >> 10) & 1;
        int rest = i >> 11;           // p*3+dh
        int dh   = rest % 3;
        int p    = rest / 3;
        int da = p / 3, db = p % 3;
        float v = 0.f;
        if (grp == 0) {
            int dw = k >> 4, ci = k & 15;
            v = w1[((((co * 16 + ci) * 3 + da) * 3 + db) * 3 + dh) * 3 + dw];
        } else if (k < 16) {
            v = w1[((((co * 16 + k) * 3 + da) * 3 + db) * 3 + dh) * 3 + 2];
        }
        w1t[i] = f2bf(v);
    } else if (bid < 2588) {                   // w2 transform
        int i = (bid - 2264) * 256 + tid;
        if (i >= 82944) return;
        int ci = i & 31;
        int co = (i >> 5) & 31;
        int t  = (i >> 10) % 9;
        int p  = (i >> 10) / 9;
        int da = p / 3, db = p % 3, dh = t / 3, dw = t % 3;
        w2t[i] = f2bf(w2[((((co * 32 + ci) * 3 + da) * 3 + db) * 3 + dh) * 3 + dw]);
    } else {                                   // stats zero
        if (tid < 128) st[tid] = 0.f;
    }
}

// ---- spill-proof inline B-frag load / MFMA round macros (NO lambdas: an
// array-by-reference lambda param defeats SROA -> scratch; round-1 lesson) ----
#define C1_LDBF(DST, BASE, GRP) { \
    _Pragma("unroll") \
    for (int dh_ = 0; dh_ < 3; ++dh_) { \
        const u16* wb_ = (BASE) + (dh_ * 2 + (GRP)) * 1024; \
        DST[dh_][0] = *(const s16x8*)(wb_ + m * 32 + kq * 8); \
        DST[dh_][1] = *(const s16x8*)(wb_ + (m + 16) * 32 + kq * 8); \
    } }

#define C1_MFMA(BF, CSHIFT) { \
    const int eb_ = (kq & 1) * 8; \
    _Pragma("unroll") \
    for (int x_ = 0; x_ < 10; ++x_) { \
        int pos_ = x_ * 66 + wseg + m + (CSHIFT); \
        s16x8 af_ = *(const s16x8*)&lds[pos_ * 24 + eb_]; \
        _Pragma("unroll") \
        for (int dh_ = 0; dh_ < 3; ++dh_) { \
            int i_ = x_ - dh_; \
            if (i_ >= 0 && i_ < 8) { \
                acc[i_][0] = __builtin_amdgcn_mfma_f32_16x16x32_bf16(af_, BF[dh_][0], acc[i_][0], 0, 0, 0); \
                acc[i_][1] = __builtin_amdgcn_mfma_f32_16x16x32_bf16(af_, BF[dh_][1], acc[i_][1], 0, 0, 0); \
            } \
        } \
    } }

// ---------------------------------------------------------------------------
// Conv1: Cin=16, K = dw(2)x ci(16) packing + dw2 group. Row-shared A-frags.
// LDS pos stride 24 u16 (48B, 16B-aligned): 2-way banks -> free.
// B-frags ping-pong pipelined one round ahead (bf0/bf1, 2 rounds/plane).
// launch_bounds (256,2): the ping-pong needs ~177 total regs; a (256,3)
// cap of 168 forces a hot-loop spill (round-1/2 lesson: +120MB scratch).
// ---------------------------------------------------------------------------
__global__ __launch_bounds__(256, 2)
void conv1_mfma(const u16* __restrict__ xT, const u16* __restrict__ w1t,
                u16* __restrict__ y1, float* __restrict__ st1)
{
    __shared__ __align__(16) u16 lds[660 * 24];   // 31680 B
    __shared__ float sred[64];

    const int tid = threadIdx.x;
    int a, b, h0;
    decode_block(blockIdx.x, a, b, h0);
    const int lane = tid & 63;
    const int wv   = tid >> 6;
    const int kq   = lane >> 4;
    const int m    = lane & 15;
    const int wseg = wv << 4;

    unsigned pm = 0;
    #pragma unroll
    for (int p = 0; p < 9; ++p) {
        int ap = a + p / 3 - 1, bp = b + p % 3 - 1;
        if (ap >= 0 && ap < D1 && bp >= 0 && bp < D2) pm |= 1u << p;
    }

    // plane-invariant staging offsets (6 granules/thread max, 16 B each)
    const int p0 = tid >> 1, g = tid & 1;
    unsigned vmask = 0;
    int goff[6];
    #pragma unroll
    for (int k = 0; k < 6; ++k) {
        int pos = p0 + 128 * k;
        int row = pos / 66, col = pos - row * 66;
        int h = h0 - 1 + row, w = col - 1;
        bool v = (pos < 660) && col >= 1 && col <= 64 && h >= 0 && h < HH;
        goff[k] = v ? (h * WW + w) * 16 + g * 8 : 0;
        vmask |= (unsigned)v << k;
    }
    const int lbase = p0 * 24 + g * 8;

    // zero pad/OOB cells once
    for (int e = tid; e < 660; e += 256) {
        int row = e / 66, col = e - row * 66;
        int h = h0 - 1 + row;
        if (col == 0 || col == 65 || h < 0 || h >= HH) {
            u16x8 z = (u16x8)0;
            *(u16x8*)&lds[e * 24]     = z;
            *(u16x8*)&lds[e * 24 + 8] = z;
        }
    }

    f32x4 acc[8][2];
    #pragma unroll
    for (int i = 0; i < 8; ++i)
        #pragma unroll
        for (int nt = 0; nt < 2; ++nt)
            acc[i][nt] = (f32x4)0.f;

    int p = 0;
    while (!((pm >> p) & 1)) ++p;

    // prologue: B-frags for (first plane, grp0) in flight before staging
    s16x8 bf0[3][2], bf1[3][2];
    C1_LDBF(bf0, w1t + p * 6144, 0);

    u16x8 pf[6];
    {
        int ap = a + p / 3 - 1, bp = b + p % 3 - 1;
        const u16* src = xT + (size_t)(ap * D2 + bp) * (HH * WW * 16);
        #pragma unroll
        for (int k = 0; k < 6; ++k)
            if ((vmask >> k) & 1) pf[k] = *(const u16x8*)(src + goff[k]);
    }

    while (p < 9) {
        int pn = p + 1;
        while (pn < 9 && !((pm >> pn) & 1)) ++pn;

        #pragma unroll
        for (int k = 0; k < 6; ++k)
            if ((vmask >> k) & 1) *(u16x8*)&lds[lbase + k * 3072] = pf[k];
        __syncthreads();

        const u16* srcn = nullptr;
        if (pn < 9)
            srcn = xT + (size_t)((a + pn / 3 - 1) * D2 + (b + pn % 3 - 1))
                      * (HH * WW * 16);

        const u16* wbase  = w1t + p * 6144;
        const u16* wbasen = w1t + (pn < 9 ? pn : p) * 6144;

        // ---- round grp0: compute bf0; prefetch (p, grp1) -> bf1
        C1_LDBF(bf1, wbase, 1);
        C1_MFMA(bf0, (kq >> 1));
        if (pn < 9) {
            #pragma unroll
            for (int k = 0; k < 3; ++k)
                if ((vmask >> k) & 1) pf[k] = *(const u16x8*)(srcn + goff[k]);
        }

        // ---- round grp1: compute bf1; prefetch (pn, grp0) -> bf0
        if (pn < 9) C1_LDBF(bf0, wbasen, 0);
        C1_MFMA(bf1, 2);
        if (pn < 9) {
            #pragma unroll
            for (int k = 3; k < 6; ++k)
                if ((vmask >> k) & 1) pf[k] = *(const u16x8*)(srcn + goff[k]);
        }

        __syncthreads();
        p = pn;
    }

    // epilogue: channel-last bf16 store + fused per-channel stats
    if (tid < 64) sred[tid] = 0.f;
    __syncthreads();

    float s[2] = {0.f, 0.f}, s2[2] = {0.f, 0.f};
    const size_t plane_out = (size_t)(a * D2 + b) * (HH * WW);
    #pragma unroll
    for (int i = 0; i < 8; ++i) {
        int h  = h0 + i;
        int w0 = wseg + kq * 4;
        #pragma unroll
        for (int nt = 0; nt < 2; ++nt) {
            int co = m + nt * 16;
            #pragma unroll
            for (int reg = 0; reg < 4; ++reg) {
                float v = acc[i][nt][reg];
                s[nt]  += v;
                s2[nt] += v * v;
                y1[(plane_out + h * WW + (w0 + reg)) * 32 + co] = f2bf(v);
            }
        }
    }
    #pragma unroll
    for (int nt = 0; nt < 2; ++nt) {
        s[nt]  += __shfl_xor(s[nt], 16);  s[nt]  += __shfl_xor(s[nt], 32);
        s2[nt] += __shfl_xor(s2[nt], 16); s2[nt] += __shfl_xor(s2[nt], 32);
    }
    if (kq == 0) {
        atomicAdd(&sred[m * 2],            s[0]);
        atomicAdd(&sred[m * 2 + 1],        s2[0]);
        atomicAdd(&sred[(m + 16) * 2],     s[1]);
        atomicAdd(&sred[(m + 16) * 2 + 1], s2[1]);
    }
    __syncthreads();
    if (tid < 64) atomicAdd(&st1[tid], sred[tid]);
}

// ---------------------------------------------------------------------------
// norm1: in-place instance-norm + leaky on y1 (channel-last bf16).
// ---------------------------------------------------------------------------
__global__ __launch_bounds__(256)
void norm1_kernel(u16* __restrict__ y1, const float* __restrict__ st1)
{
    const int tid = threadIdx.x;
    const int q   = tid & 3;
    const float invN = 1.f / (float)SPATIAL;
    float mean[8], scl[8];
    #pragma unroll
    for (int j = 0; j < 8; ++j) {
        int ci  = q * 8 + j;
        float mu = st1[ci * 2] * invN;
        float va = st1[ci * 2 + 1] * invN - mu * mu;
        mean[j] = mu;
        scl[j]  = rsqrtf(va + EPS);
    }
    #pragma unroll
    for (int j4 = 0; j4 < 4; ++j4) {
        size_t gidx = (size_t)blockIdx.x * 1024 + j4 * 256 + tid;
        u16x8* ptr = (u16x8*)(y1 + gidx * 8);
        u16x8 v = *ptr;
        u16x8 o;
        #pragma unroll
        for (int j = 0; j < 8; ++j)
            o[j] = f2bf(leaky((bf2f(v[j]) - mean[j]) * scl[j]));
        *ptr = o;
    }
}

#define C2_LDBF(DST, BASE, DW) { \
    _Pragma("unroll") \
    for (int dh_ = 0; dh_ < 3; ++dh_) { \
        const u16* wb_ = (BASE) + (dh_ * 3 + (DW)) * 1024; \
        DST[dh_][0] = *(const s16x8*)(wb_ + m * 32 + kq * 8); \
        DST[dh_][1] = *(const s16x8*)(wb_ + (m + 16) * 32 + kq * 8); \
    } }

#define C2_MFMA(BF, DW) { \
    _Pragma("unroll") \
    for (int x_ = 0; x_ < 10; ++x_) { \
        int pos_ = x_ * 66 + wseg + (DW) + m; \
        s16x8 af_ = *(const s16x8*)&lds[pos_ * 40 + kq * 8]; \
        _Pragma("unroll") \
        for (int dh_ = 0; dh_ < 3; ++dh_) { \
            int i_ = x_ - dh_; \
            if (i_ >= 0 && i_ < 8) { \
                acc[i_][0] = __builtin_amdgcn_mfma_f32_16x16x32_bf16(af_, BF[dh_][0], acc[i_][0], 0, 0, 0); \
                acc[i_][1] = __builtin_amdgcn_mfma_f32_16x16x32_bf16(af_, BF[dh_][1], acc[i_][1], 0, 0, 0); \
            } \
        } \
    } }

#define C2_PF(K0, K1) { \
    _Pragma("unroll") \
    for (int k_ = (K0); k_ < (K1); ++k_) \
        if ((vmask >> k_) & 1) pf[k_] = *(const u16x8*)(srcn + goff[k_]); }

// ---------------------------------------------------------------------------
// Conv2: Cin=32, row-shared A-frags; LDS pos stride 40 u16 (80B): 2-way free.
// B-frags ping-pong pipelined one round ahead (bfA/bfB, 3 rounds/plane,
// one 6-frag register copy per plane restores the entry invariant).
// launch_bounds (256,2): see conv1 note — (256,3)'s 168-reg cap spills.
// ---------------------------------------------------------------------------
__global__ __launch_bounds__(256, 2)
void conv2_mfma(const u16* __restrict__ y1, const u16* __restrict__ w2t,
                u16* __restrict__ y2, float* __restrict__ st2)
{
    __shared__ __align__(16) u16 lds[660 * 40];   // 52800 B
    __shared__ float sred[64];

    const int tid = threadIdx.x;
    int a, b, h0;
    decode_block(blockIdx.x, a, b, h0);
    const int lane = tid & 63;
    const int wv   = tid >> 6;
    const int kq   = lane >> 4;
    const int m    = lane & 15;
    const int wseg = wv << 4;

    unsigned pm = 0;
    #pragma unroll
    for (int p = 0; p < 9; ++p) {
        int ap = a + p / 3 - 1, bp = b + p % 3 - 1;
        if (ap >= 0 && ap < D1 && bp >= 0 && bp < D2) pm |= 1u << p;
    }

    // plane-invariant staging offsets (11 granules/thread max)
    const int p0 = tid >> 2, q = tid & 3;
    unsigned vmask = 0;
    int goff[11];
    #pragma unroll
    for (int k = 0; k < 11; ++k) {
        int pos = p0 + 64 * k;
        int row = pos / 66, col = pos - row * 66;
        int h = h0 - 1 + row, w = col - 1;
        bool v = (pos < 660) && col >= 1 && col <= 64 && h >= 0 && h < HH;
        goff[k] = v ? (h * WW + w) * 32 + q * 8 : 0;
        vmask |= (unsigned)v << k;
    }
    const int lbase = p0 * 40 + q * 8;

    for (int e = tid; e < 660; e += 256) {
        int row = e / 66, col = e - row * 66;
        int h = h0 - 1 + row;
        if (col == 0 || col == 65 || h < 0 || h >= HH) {
            u16x8 z = (u16x8)0;
            #pragma unroll
            for (int gg = 0; gg < 4; ++gg)
                *(u16x8*)&lds[e * 40 + gg * 8] = z;
        }
    }

    f32x4 acc[8][2];
    #pragma unroll
    for (int i = 0; i < 8; ++i)
        #pragma unroll
        for (int nt = 0; nt < 2; ++nt)
            acc[i][nt] = (f32x4)0.f;

    int p = 0;
    while (!((pm >> p) & 1)) ++p;

    // prologue: B-frags for (first plane, dw0) in flight before staging
    s16x8 bfA[3][2], bfB[3][2];
    C2_LDBF(bfA, w2t + p * 9216, 0);

    u16x8 pf[11];
    {
        int ap = a + p / 3 - 1, bp = b + p % 3 - 1;
        const u16* src = y1 + (size_t)(ap * D2 + bp) * (HH * WW * 32);
        #pragma unroll
        for (int k = 0; k < 11; ++k)
            if ((vmask >> k) & 1) pf[k] = *(const u16x8*)(src + goff[k]);
    }

    while (p < 9) {
        int pn = p + 1;
        while (pn < 9 && !((pm >> pn) & 1)) ++pn;

        #pragma unroll
        for (int k = 0; k < 11; ++k)
            if ((vmask >> k) & 1) *(u16x8*)&lds[lbase + k * 2560] = pf[k];
        __syncthreads();

        const u16* srcn = nullptr;
        if (pn < 9)
            srcn = y1 + (size_t)((a + pn / 3 - 1) * D2 + (b + pn % 3 - 1))
                      * (HH * WW * 32);

        const u16* wbase  = w2t + p * 9216;
        const u16* wbasen = w2t + (pn < 9 ? pn : p) * 9216;

        // r0 (dw0): compute bfA; prefetch (p, dw1) -> bfB
        C2_LDBF(bfB, wbase, 1);
        C2_MFMA(bfA, 0);
        if (pn < 9) C2_PF(0, 4);

        // r1 (dw1): compute bfB; prefetch (p, dw2) -> bfA (dw0 data dead)
        C2_LDBF(bfA, wbase, 2);
        C2_MFMA(bfB, 1);
        if (pn < 9) C2_PF(4, 8);

        // r2 (dw2): compute bfA; prefetch (pn, dw0) -> bfB
        if (pn < 9) C2_LDBF(bfB, wbasen, 0);
        C2_MFMA(bfA, 2);
        if (pn < 9) C2_PF(8, 11);

        // restore entry invariant: bfA holds next plane's dw0 (6 v_mov_b32x4)
        if (pn < 9) {
            #pragma unroll
            for (int dh = 0; dh < 3; ++dh) {
                bfA[dh][0] = bfB[dh][0];
                bfA[dh][1] = bfB[dh][1];
            }
        }

        __syncthreads();
        p = pn;
    }

    // epilogue: channel-first bf16 + fused stats
    if (tid < 64) sred[tid] = 0.f;
    __syncthreads();

    float s[2] = {0.f, 0.f}, s2[2] = {0.f, 0.f};
    #pragma unroll
    for (int i = 0; i < 8; ++i) {
        int h  = h0 + i;
        int w0 = wseg + kq * 4;
        #pragma unroll
        for (int nt = 0; nt < 2; ++nt) {
            int co = m + nt * 16;
            u16x4 pk;
            #pragma unroll
            for (int reg = 0; reg < 4; ++reg) {
                float v = acc[i][nt][reg];
                s[nt]  += v;
                s2[nt] += v * v;
                pk[reg] = f2bf(v);
            }
            size_t off = ((size_t)(co * D1 + a) * D2 + b) * (HH * WW) + h * WW + w0;
            *(u16x4*)(y2 + off) = pk;
        }
    }
    #pragma unroll
    for (int nt = 0; nt < 2; ++nt) {
        s[nt]  += __shfl_xor(s[nt], 16);  s[nt]  += __shfl_xor(s[nt], 32);
        s2[nt] += __shfl_xor(s2[nt], 16); s2[nt] += __shfl_xor(s2[nt], 32);
    }
    if (kq == 0) {
        atomicAdd(&sred[m * 2],            s[0]);
        atomicAdd(&sred[m * 2 + 1],        s2[0]);
        atomicAdd(&sred[(m + 16) * 2],     s[1]);
        atomicAdd(&sred[(m + 16) * 2 + 1], s2[1]);
    }
    __syncthreads();
    if (tid < 64) atomicAdd(&st2[tid], sred[tid]);
}

// ---------------------------------------------------------------------------
// Final: norm + leaky, bf16 channel-first -> fp32 channel-first d_out
// ---------------------------------------------------------------------------
__global__ __launch_bounds__(256)
void norm2_kernel(const u16* __restrict__ y2, const float* __restrict__ st2,
                  float* __restrict__ out)
{
    size_t i4 = (size_t)blockIdx.x * 256 + threadIdx.x;
    int c = (int)(i4 >> 17);
    const float invN = 1.f / (float)SPATIAL;
    float mu = st2[c * 2] * invN;
    float va = st2[c * 2 + 1] * invN - mu * mu;
    float sc = rsqrtf(va + EPS);
    u16x4 v = *(const u16x4*)(y2 + i4 * 4);
    float4 o;
    o.x = leaky((bf2f(v[0]) - mu) * sc);
    o.y = leaky((bf2f(v[1]) - mu) * sc);
    o.z = leaky((bf2f(v[2]) - mu) * sc);
    o.w = leaky((bf2f(v[3]) - mu) * sc);
    *(float4*)(out + i4 * 4) = o;
}

// ---------------------------------------------------------------------------
extern "C" void kernel_launch(void* const* d_in, const int* in_sizes, int n_in,
                              void* d_out, int out_size, void* d_ws, size_t ws_size,
                              hipStream_t stream)
{
    const float* image = (const float*)d_in[0];
    const float* w1    = (const float*)d_in[1];
    const float* w2    = (const float*)d_in[2];
    float* out = (float*)d_out;

    // ws: [0,32MB) imgT (reused as y2) | [32MB,64MB) y1 | [64MB,+512B) stats
    u16*   imgT = (u16*)d_ws;
    u16*   y1   = (u16*)((char*)d_ws + 33554432);
    u16*   y2   = imgT;
    float* st   = (float*)((char*)d_ws + 67108864);
    float* st1  = st;
    float* st2  = st + 64;

    // weight tables live in d_out's tail; dead before norm2 overwrites d_out
    u16* w1t = (u16*)((char*)d_out + 66832384);   // 55296 bf16
    u16* w2t = (u16*)((char*)d_out + 66942976);   // 82944 bf16

    prep<<<2589, 256, 0, stream>>>(image, w1, w2, imgT, w1t, w2t, st);

    conv1_mfma<<<1024, 256, 0, stream>>>(imgT, w1t, y1, st1);
    norm1_kernel<<<2048, 256, 0, stream>>>(y1, st1);
    conv2_mfma<<<1024, 256, 0, stream>>>(y1, w2t, y2, st2);
    norm2_kernel<<<16384, 256, 0, stream>>>(y2, st2, out);
}

// Round 4
// 248.825 us; speedup vs baseline: 1.4497x; 1.0340x over previous
//
#include <hip/hip_runtime.h>

#define D1 8
#define D2 16
#define HH 64
#define WW 64
#define SPATIAL (D1*D2*HH*WW)   // 524288
#define EPS 1e-5f
#define NEG 0.2f

typedef unsigned short u16;
typedef __attribute__((ext_vector_type(8))) short s16x8;
typedef __attribute__((ext_vector_type(8))) unsigned short u16x8;
typedef __attribute__((ext_vector_type(4))) unsigned short u16x4;
typedef __attribute__((ext_vector_type(4))) float f32x4;

__device__ __forceinline__ u16 f2bf(float f) {
    unsigned int u = __builtin_bit_cast(unsigned int, f);
    return (u16)((u + 0x7FFFu + ((u >> 16) & 1u)) >> 16);   // RNE
}
__device__ __forceinline__ float bf2f(u16 u) {
    unsigned int v = ((unsigned int)u) << 16;
    return __builtin_bit_cast(float, v);
}
__device__ __forceinline__ float leaky(float x) {
    return x >= 0.f ? x : NEG * x;
}

// XCD swizzle: b-PAIR per XCD (db-halo L2 reuse); h-tiles+a consecutive.
__device__ __forceinline__ void decode_block(int flat, int& a, int& b, int& h0) {
    int xcd  = flat & 7;
    int slot = flat >> 3;
    int ht   = slot & 7;
    int b0   = (slot >> 3) & 1;
    a        = (slot >> 4) & 7;
    b        = xcd * 2 + b0;
    h0       = ht * 8;
}

// ---------------------------------------------------------------------------
// prep: fused imgtrans (blocks 0..2047) + wtrans1 (2048..2263) +
//       wtrans2 (2264..2587) + stats-zero (2588).
// w1t: [p(9)][dh(3)][grp(2)][co(32)][k(32)]
// w2t: [p(9)][tap(9)][co(32)][ci(32)]
// imgT: [spatial][ci16] channel-last bf16
// ---------------------------------------------------------------------------
__global__ __launch_bounds__(256)
void prep(const float* __restrict__ img, const float* __restrict__ w1,
          const float* __restrict__ w2, u16* __restrict__ imgT,
          u16* __restrict__ w1t, u16* __restrict__ w2t, float* __restrict__ st)
{
    const int bid = blockIdx.x;
    const int tid = threadIdx.x;
    if (bid < 2048) {                          // image transpose
        int p = bid * 256 + tid;
        u16 r[16];
        #pragma unroll
        for (int c = 0; c < 16; ++c)
            r[c] = f2bf(img[(size_t)c * SPATIAL + p]);
        u16x8 lo, hi;
        #pragma unroll
        for (int j = 0; j < 8; ++j) { lo[j] = r[j]; hi[j] = r[8 + j]; }
        u16x8* dst = (u16x8*)(imgT + (size_t)p * 16);
        dst[0] = lo;
        dst[1] = hi;
    } else if (bid < 2264) {                   // w1 transform
        int i = (bid - 2048) * 256 + tid;
        if (i >= 55296) return;
        int k    = i & 31;
        int co   = (i >> 5) & 31;
        int grp  = (i >> 10) & 1;
        int rest = i >> 11;           // p*3+dh
        int dh   = rest % 3;
        int p    = rest / 3;
        int da = p / 3, db = p % 3;
        float v = 0.f;
        if (grp == 0) {
            int dw = k >> 4, ci = k & 15;
            v = w1[((((co * 16 + ci) * 3 + da) * 3 + db) * 3 + dh) * 3 + dw];
        } else if (k < 16) {
            v = w1[((((co * 16 + k) * 3 + da) * 3 + db) * 3 + dh) * 3 + 2];
        }
        w1t[i] = f2bf(v);
    } else if (bid < 2588) {                   // w2 transform
        int i = (bid - 2264) * 256 + tid;
        if (i >= 82944) return;
        int ci = i & 31;
        int co = (i >> 5) & 31;
        int t  = (i >> 10) % 9;
        int p  = (i >> 10) / 9;
        int da = p / 3, db = p % 3, dh = t / 3, dw = t % 3;
        w2t[i] = f2bf(w2[((((co * 32 + ci) * 3 + da) * 3 + db) * 3 + dh) * 3 + dw]);
    } else {                                   // stats zero
        if (tid < 128) st[tid] = 0.f;
    }
}

// ---- spill-proof inline macros (NO lambdas / array-ref params: defeats
// SROA -> scratch; round-1 lesson). Staging offsets are AFFINE in k
// (gbase + k*2048): no offset array -> ~10 fewer regs (round-3 lesson:
// 2 blocks/CU was the limiter; target <=170 total regs for 3/CU). ----
#define C1_LDBF(DST, BASE, GRP) { \
    _Pragma("unroll") \
    for (int dh_ = 0; dh_ < 3; ++dh_) { \
        const u16* wb_ = (BASE) + (dh_ * 2 + (GRP)) * 1024; \
        DST[dh_][0] = *(const s16x8*)(wb_ + m * 32 + kq * 8); \
        DST[dh_][1] = *(const s16x8*)(wb_ + (m + 16) * 32 + kq * 8); \
    } }

#define C1_MFMA(BF, CSHIFT) { \
    const int eb_ = (kq & 1) * 8; \
    _Pragma("unroll") \
    for (int x_ = 0; x_ < 10; ++x_) { \
        int pos_ = x_ * 66 + wseg + m + (CSHIFT); \
        s16x8 af_ = *(const s16x8*)&lds[pos_ * 24 + eb_]; \
        _Pragma("unroll") \
        for (int dh_ = 0; dh_ < 3; ++dh_) { \
            int i_ = x_ - dh_; \
            if (i_ >= 0 && i_ < 8) { \
                acc[i_][0] = __builtin_amdgcn_mfma_f32_16x16x32_bf16(af_, BF[dh_][0], acc[i_][0], 0, 0, 0); \
                acc[i_][1] = __builtin_amdgcn_mfma_f32_16x16x32_bf16(af_, BF[dh_][1], acc[i_][1], 0, 0, 0); \
            } \
        } \
    } }

#define C1_PF(K0, K1) { \
    _Pragma("unroll") \
    for (int k_ = (K0); k_ < (K1); ++k_) \
        if ((vmask >> k_) & 1) pf[k_] = *(const u16x8*)(srcn + gbase + k_ * 2048); }

// ---------------------------------------------------------------------------
// Conv1: Cin=16, K = dw(2)x ci(16) packing + dw2 group. Row-shared A-frags.
// LDS pos stride 24 u16 (48B, 16B-aligned): 2-way banks -> free.
// Staging: only the 1280 stageable granules (64 cols x 10 rows x 2) ->
// exactly 5/thread, affine offsets. B-frags ping-pong within plane; the
// cross-plane (pn,grp0) load sits after the tail barrier (covered by the
// next stage+barrier), flattening peak pressure for 3 blocks/CU.
// ---------------------------------------------------------------------------
__global__ __launch_bounds__(256, 3)
void conv1_mfma(const u16* __restrict__ xT, const u16* __restrict__ w1t,
                u16* __restrict__ y1, float* __restrict__ st1)
{
    __shared__ __align__(16) u16 lds[660 * 24];   // 31680 B
    __shared__ float sred[64];

    const int tid = threadIdx.x;
    int a, b, h0;
    decode_block(blockIdx.x, a, b, h0);
    const int lane = tid & 63;
    const int wv   = tid >> 6;
    const int kq   = lane >> 4;
    const int m    = lane & 15;
    const int wseg = wv << 4;

    unsigned pm = 0;
    #pragma unroll
    for (int p = 0; p < 9; ++p) {
        int ap = a + p / 3 - 1, bp = b + p % 3 - 1;
        if (ap >= 0 && ap < D1 && bp >= 0 && bp < D2) pm |= 1u << p;
    }

    // staging geometry: thread -> (rows 2k+hi, col p0c+1, half g), k=0..4
    const int p0f  = tid >> 1, g = tid & 1;
    const int hi   = p0f >> 6;            // 0/1
    const int p0c  = p0f & 63;            // col-1
    unsigned vmask = 0;
    #pragma unroll
    for (int k = 0; k < 5; ++k) {
        int h = h0 - 1 + 2 * k + hi;
        if (h >= 0 && h < HH) vmask |= 1u << k;
    }
    const int gbase = ((h0 - 1 + hi) * WW + p0c) * 16 + g * 8;   // + k*2048
    const int lbase = (hi * 66 + p0c + 1) * 24 + g * 8;          // + k*3168

    // zero pad/OOB cells once
    for (int e = tid; e < 660; e += 256) {
        int row = e / 66, col = e - row * 66;
        int h = h0 - 1 + row;
        if (col == 0 || col == 65 || h < 0 || h >= HH) {
            u16x8 z = (u16x8)0;
            *(u16x8*)&lds[e * 24]     = z;
            *(u16x8*)&lds[e * 24 + 8] = z;
        }
    }

    f32x4 acc[8][2];
    #pragma unroll
    for (int i = 0; i < 8; ++i)
        #pragma unroll
        for (int nt = 0; nt < 2; ++nt)
            acc[i][nt] = (f32x4)0.f;

    int p = 0;
    while (!((pm >> p) & 1)) ++p;

    // prologue: (first plane, grp0) B-frags + first A-tile in flight
    s16x8 bfX[3][2], bfY[3][2];
    C1_LDBF(bfX, w1t + p * 6144, 0);

    u16x8 pf[5];
    {
        const u16* srcn = xT + (size_t)((a + p / 3 - 1) * D2 + (b + p % 3 - 1))
                             * (HH * WW * 16);
        C1_PF(0, 5);
    }

    while (p < 9) {
        int pn = p + 1;
        while (pn < 9 && !((pm >> pn) & 1)) ++pn;

        #pragma unroll
        for (int k = 0; k < 5; ++k)
            if ((vmask >> k) & 1) *(u16x8*)&lds[lbase + k * 3168] = pf[k];
        __syncthreads();

        const u16* srcn = nullptr;
        if (pn < 9)
            srcn = xT + (size_t)((a + pn / 3 - 1) * D2 + (b + pn % 3 - 1))
                      * (HH * WW * 16);

        const u16* wbase = w1t + p * 6144;

        // ---- round grp0: compute bfX; load (p, grp1) -> bfY
        C1_LDBF(bfY, wbase, 1);
        C1_MFMA(bfX, (kq >> 1));
        if (pn < 9) C1_PF(0, 3);

        // ---- round grp1: compute bfY
        C1_MFMA(bfY, 2);
        if (pn < 9) C1_PF(3, 5);

        __syncthreads();
        // cross-plane (pn, grp0) -> bfX; covered by next stage writes+barrier
        if (pn < 9) C1_LDBF(bfX, w1t + pn * 6144, 0);
        p = pn;
    }

    // epilogue: channel-last bf16 store + fused per-channel stats
    if (tid < 64) sred[tid] = 0.f;
    __syncthreads();

    float s[2] = {0.f, 0.f}, s2[2] = {0.f, 0.f};
    const size_t plane_out = (size_t)(a * D2 + b) * (HH * WW);
    #pragma unroll
    for (int i = 0; i < 8; ++i) {
        int h  = h0 + i;
        int w0 = wseg + kq * 4;
        #pragma unroll
        for (int nt = 0; nt < 2; ++nt) {
            int co = m + nt * 16;
            #pragma unroll
            for (int reg = 0; reg < 4; ++reg) {
                float v = acc[i][nt][reg];
                s[nt]  += v;
                s2[nt] += v * v;
                y1[(plane_out + h * WW + (w0 + reg)) * 32 + co] = f2bf(v);
            }
        }
    }
    #pragma unroll
    for (int nt = 0; nt < 2; ++nt) {
        s[nt]  += __shfl_xor(s[nt], 16);  s[nt]  += __shfl_xor(s[nt], 32);
        s2[nt] += __shfl_xor(s2[nt], 16); s2[nt] += __shfl_xor(s2[nt], 32);
    }
    if (kq == 0) {
        atomicAdd(&sred[m * 2],            s[0]);
        atomicAdd(&sred[m * 2 + 1],        s2[0]);
        atomicAdd(&sred[(m + 16) * 2],     s[1]);
        atomicAdd(&sred[(m + 16) * 2 + 1], s2[1]);
    }
    __syncthreads();
    if (tid < 64) atomicAdd(&st1[tid], sred[tid]);
}

// ---------------------------------------------------------------------------
// norm1: in-place instance-norm + leaky on y1 (channel-last bf16).
// ---------------------------------------------------------------------------
__global__ __launch_bounds__(256)
void norm1_kernel(u16* __restrict__ y1, const float* __restrict__ st1)
{
    const int tid = threadIdx.x;
    const int q   = tid & 3;
    const float invN = 1.f / (float)SPATIAL;
    float mean[8], scl[8];
    #pragma unroll
    for (int j = 0; j < 8; ++j) {
        int ci  = q * 8 + j;
        float mu = st1[ci * 2] * invN;
        float va = st1[ci * 2 + 1] * invN - mu * mu;
        mean[j] = mu;
        scl[j]  = rsqrtf(va + EPS);
    }
    #pragma unroll
    for (int j4 = 0; j4 < 4; ++j4) {
        size_t gidx = (size_t)blockIdx.x * 1024 + j4 * 256 + tid;
        u16x8* ptr = (u16x8*)(y1 + gidx * 8);
        u16x8 v = *ptr;
        u16x8 o;
        #pragma unroll
        for (int j = 0; j < 8; ++j)
            o[j] = f2bf(leaky((bf2f(v[j]) - mean[j]) * scl[j]));
        *ptr = o;
    }
}

#define C2_LDBF(DST, BASE, DW) { \
    _Pragma("unroll") \
    for (int dh_ = 0; dh_ < 3; ++dh_) { \
        const u16* wb_ = (BASE) + (dh_ * 3 + (DW)) * 1024; \
        DST[dh_][0] = *(const s16x8*)(wb_ + m * 32 + kq * 8); \
        DST[dh_][1] = *(const s16x8*)(wb_ + (m + 16) * 32 + kq * 8); \
    } }

#define C2_MFMA(BF, DW) { \
    _Pragma("unroll") \
    for (int x_ = 0; x_ < 10; ++x_) { \
        int pos_ = x_ * 66 + wseg + (DW) + m; \
        s16x8 af_ = *(const s16x8*)&lds[pos_ * 40 + kq * 8]; \
        _Pragma("unroll") \
        for (int dh_ = 0; dh_ < 3; ++dh_) { \
            int i_ = x_ - dh_; \
            if (i_ >= 0 && i_ < 8) { \
                acc[i_][0] = __builtin_amdgcn_mfma_f32_16x16x32_bf16(af_, BF[dh_][0], acc[i_][0], 0, 0, 0); \
                acc[i_][1] = __builtin_amdgcn_mfma_f32_16x16x32_bf16(af_, BF[dh_][1], acc[i_][1], 0, 0, 0); \
            } \
        } \
    } }

#define C2_PF(K0, K1) { \
    _Pragma("unroll") \
    for (int k_ = (K0); k_ < (K1); ++k_) \
        if ((vmask >> k_) & 1) pf[k_] = *(const u16x8*)(srcn + gbase + k_ * 2048); }

// ---------------------------------------------------------------------------
// Conv2: Cin=32, row-shared A-frags; LDS pos stride 40 u16 (80B): 2-way free.
// Staging: only the 2560 stageable granules (64 cols x 10 rows x 4) ->
// exactly 10/thread (pf[10], was 11), affine offsets (goff array gone).
// B-frags ping-pong within plane; cross-plane (pn,dw0) load after the tail
// barrier. Targets <=170 total regs -> 3 blocks/CU (round-3 limiter).
// ---------------------------------------------------------------------------
__global__ __launch_bounds__(256, 3)
void conv2_mfma(const u16* __restrict__ y1, const u16* __restrict__ w2t,
                u16* __restrict__ y2, float* __restrict__ st2)
{
    __shared__ __align__(16) u16 lds[660 * 40];   // 52800 B
    __shared__ float sred[64];

    const int tid = threadIdx.x;
    int a, b, h0;
    decode_block(blockIdx.x, a, b, h0);
    const int lane = tid & 63;
    const int wv   = tid >> 6;
    const int kq   = lane >> 4;
    const int m    = lane & 15;
    const int wseg = wv << 4;

    unsigned pm = 0;
    #pragma unroll
    for (int p = 0; p < 9; ++p) {
        int ap = a + p / 3 - 1, bp = b + p % 3 - 1;
        if (ap >= 0 && ap < D1 && bp >= 0 && bp < D2) pm |= 1u << p;
    }

    // staging geometry: thread -> (row k, col p0+1, quarter q), k=0..9
    const int p0 = tid >> 2, q = tid & 3;
    unsigned vmask = 0;
    #pragma unroll
    for (int k = 0; k < 10; ++k) {
        int h = h0 - 1 + k;
        if (h >= 0 && h < HH) vmask |= 1u << k;
    }
    const int gbase = ((h0 - 1) * WW + p0) * 32 + q * 8;   // + k*2048
    const int lbase = (p0 + 1) * 40 + q * 8;               // + k*2640

    for (int e = tid; e < 660; e += 256) {
        int row = e / 66, col = e - row * 66;
        int h = h0 - 1 + row;
        if (col == 0 || col == 65 || h < 0 || h >= HH) {
            u16x8 z = (u16x8)0;
            #pragma unroll
            for (int gg = 0; gg < 4; ++gg)
                *(u16x8*)&lds[e * 40 + gg * 8] = z;
        }
    }

    f32x4 acc[8][2];
    #pragma unroll
    for (int i = 0; i < 8; ++i)
        #pragma unroll
        for (int nt = 0; nt < 2; ++nt)
            acc[i][nt] = (f32x4)0.f;

    int p = 0;
    while (!((pm >> p) & 1)) ++p;

    // prologue: (first plane, dw0) B-frags + first A-tile in flight
    s16x8 bfX[3][2], bfY[3][2];
    C2_LDBF(bfX, w2t + p * 9216, 0);

    u16x8 pf[10];
    {
        const u16* srcn = y1 + (size_t)((a + p / 3 - 1) * D2 + (b + p % 3 - 1))
                             * (HH * WW * 32);
        C2_PF(0, 10);
    }

    while (p < 9) {
        int pn = p + 1;
        while (pn < 9 && !((pm >> pn) & 1)) ++pn;

        #pragma unroll
        for (int k = 0; k < 10; ++k)
            if ((vmask >> k) & 1) *(u16x8*)&lds[lbase + k * 2640] = pf[k];
        __syncthreads();

        const u16* srcn = nullptr;
        if (pn < 9)
            srcn = y1 + (size_t)((a + pn / 3 - 1) * D2 + (b + pn % 3 - 1))
                      * (HH * WW * 32);

        const u16* wbase = w2t + p * 9216;

        // r0 (dw0): compute bfX; load (p, dw1) -> bfY
        C2_LDBF(bfY, wbase, 1);
        C2_MFMA(bfX, 0);
        if (pn < 9) C2_PF(0, 4);

        // r1 (dw1): compute bfY; load (p, dw2) -> bfX (dw0 data dead)
        C2_LDBF(bfX, wbase, 2);
        C2_MFMA(bfY, 1);
        if (pn < 9) C2_PF(4, 7);

        // r2 (dw2): compute bfX
        C2_MFMA(bfX, 2);
        if (pn < 9) C2_PF(7, 10);

        __syncthreads();
        // cross-plane (pn, dw0) -> bfX; covered by next stage writes+barrier
        if (pn < 9) C2_LDBF(bfX, w2t + pn * 9216, 0);
        p = pn;
    }

    // epilogue: channel-first bf16 + fused stats
    if (tid < 64) sred[tid] = 0.f;
    __syncthreads();

    float s[2] = {0.f, 0.f}, s2[2] = {0.f, 0.f};
    #pragma unroll
    for (int i = 0; i < 8; ++i) {
        int h  = h0 + i;
        int w0 = wseg + kq * 4;
        #pragma unroll
        for (int nt = 0; nt < 2; ++nt) {
            int co = m + nt * 16;
            u16x4 pk;
            #pragma unroll
            for (int reg = 0; reg < 4; ++reg) {
                float v = acc[i][nt][reg];
                s[nt]  += v;
                s2[nt] += v * v;
                pk[reg] = f2bf(v);
            }
            size_t off = ((size_t)(co * D1 + a) * D2 + b) * (HH * WW) + h * WW + w0;
            *(u16x4*)(y2 + off) = pk;
        }
    }
    #pragma unroll
    for (int nt = 0; nt < 2; ++nt) {
        s[nt]  += __shfl_xor(s[nt], 16);  s[nt]  += __shfl_xor(s[nt], 32);
        s2[nt] += __shfl_xor(s2[nt], 16); s2[nt] += __shfl_xor(s2[nt], 32);
    }
    if (kq == 0) {
        atomicAdd(&sred[m * 2],            s[0]);
        atomicAdd(&sred[m * 2 + 1],        s2[0]);
        atomicAdd(&sred[(m + 16) * 2],     s[1]);
        atomicAdd(&sred[(m + 16) * 2 + 1], s2[1]);
    }
    __syncthreads();
    if (tid < 64) atomicAdd(&st2[tid], sred[tid]);
}

// ---------------------------------------------------------------------------
// Final: norm + leaky, bf16 channel-first -> fp32 channel-first d_out
// ---------------------------------------------------------------------------
__global__ __launch_bounds__(256)
void norm2_kernel(const u16* __restrict__ y2, const float* __restrict__ st2,
                  float* __restrict__ out)
{
    size_t i4 = (size_t)blockIdx.x * 256 + threadIdx.x;
    int c = (int)(i4 >> 17);
    const float invN = 1.f / (float)SPATIAL;
    float mu = st2[c * 2] * invN;
    float va = st2[c * 2 + 1] * invN - mu * mu;
    float sc = rsqrtf(va + EPS);
    u16x4 v = *(const u16x4*)(y2 + i4 * 4);
    float4 o;
    o.x = leaky((bf2f(v[0]) - mu) * sc);
    o.y = leaky((bf2f(v[1]) - mu) * sc);
    o.z = leaky((bf2f(v[2]) - mu) * sc);
    o.w = leaky((bf2f(v[3]) - mu) * sc);
    *(float4*)(out + i4 * 4) = o;
}

// ---------------------------------------------------------------------------
extern "C" void kernel_launch(void* const* d_in, const int* in_sizes, int n_in,
                              void* d_out, int out_size, void* d_ws, size_t ws_size,
                              hipStream_t stream)
{
    const float* image = (const float*)d_in[0];
    const float* w1    = (const float*)d_in[1];
    const float* w2    = (const float*)d_in[2];
    float* out = (float*)d_out;

    // ws: [0,32MB) imgT (reused as y2) | [32MB,64MB) y1 | [64MB,+512B) stats
    u16*   imgT = (u16*)d_ws;
    u16*   y1   = (u16*)((char*)d_ws + 33554432);
    u16*   y2   = imgT;
    float* st   = (float*)((char*)d_ws + 67108864);
    float* st1  = st;
    float* st2  = st + 64;

    // weight tables live in d_out's tail; dead before norm2 overwrites d_out
    u16* w1t = (u16*)((char*)d_out + 66832384);   // 55296 bf16
    u16* w2t = (u16*)((char*)d_out + 66942976);   // 82944 bf16

    prep<<<2589, 256, 0, stream>>>(image, w1, w2, imgT, w1t, w2t, st);

    conv1_mfma<<<1024, 256, 0, stream>>>(imgT, w1t, y1, st1);
    norm1_kernel<<<2048, 256, 0, stream>>>(y1, st1);
    conv2_mfma<<<1024, 256, 0, stream>>>(y1, w2t, y2, st2);
    norm2_kernel<<<16384, 256, 0, stream>>>(y2, st2, out);
}